// Round 1
// 1142.827 us; speedup vs baseline: 2.0232x; 2.0232x over previous
//
#include <hip/hip_runtime.h>
#include <hip/hip_bf16.h>
#include <math.h>

#define NTOK 8192
#define DIM  1024
#define FFN  4096
#define NEXP 10

#define NT_SH (NTOK / 128)             // 64 shared m-tiles
#define NT_RT (NTOK / 128 + NEXP - 1)  // 73 = worst-case sum of ceil(cnt_e/128)
#define NY01  ((FFN + DIM) / 128)      // 40 n-tiles: 32 for W1, 8 for Wg
#define NY2   (DIM / 128)              // 8

typedef __attribute__((ext_vector_type(8))) short bf16x8;   // 8 bf16 = 4 VGPR (MFMA A/B frag)
typedef __attribute__((ext_vector_type(4))) float f32x4;    // MFMA C/D frag

static __device__ __forceinline__ unsigned short f2bf(float f) {
  __hip_bfloat16 h = __float2bfloat16(f);
  return *reinterpret_cast<unsigned short*>(&h);
}

// async global->LDS, 16B/lane. LDS dest = wave-uniform base + lane*16.
static __device__ __forceinline__ void gld_lds16(const unsigned short* g, unsigned short* l) {
  __builtin_amdgcn_global_load_lds((const __attribute__((address_space(1))) unsigned int*)g,
                                   (__attribute__((address_space(3))) unsigned int*)l,
                                   16, 0, 0);
}

// flat block id -> (bx, by): XCD-chunked bijective swizzle (m204) so each XCD owns a
// contiguous logical range, then by-groups of G so G B-panels + 1 A-panel stay L2-resident.
template <int NX, int NY, int G>
static __device__ __forceinline__ void map_block(int orig, int& bx, int& by) {
  const int n = NX * NY;
  int xcd = orig & 7, o = orig >> 3;
  const int q = n >> 3, r = n & 7;
  int id = (xcd < r ? xcd * (q + 1) : r * (q + 1) + (xcd - r) * q) + o;
  const int gsz = NX * G;          // NY % G == 0 for all instantiations
  int grp = id / gsz;
  int rem = id - grp * gsz;
  bx = rem / G;                    // by varies fastest: A-panel reused G consecutive blocks
  by = grp * G + (rem - bx * G);
}

// ---------------- routing ----------------
__global__ void k_zero(int* cnt) { if (threadIdx.x < NEXP) cnt[threadIdx.x] = 0; }

__global__ void k_count(const int* __restrict__ dom, int* __restrict__ cnt, int* __restrict__ pos) {
  int t = blockIdx.x * 256 + threadIdx.x;
  if (t < NTOK) pos[t] = atomicAdd(&cnt[dom[t]], 1);
}

// prefix offsets + exact (expert, m-tile) work list: kills the 89% empty-block dilution
__global__ void k_offsets(const int* __restrict__ cnt, int* __restrict__ segoff,
                          int* __restrict__ tilemap, int* __restrict__ ntiles) {
  if (threadIdx.x == 0) {
    int s = 0, k = 0;
    for (int e = 0; e < NEXP; e++) {
      segoff[e] = s;
      int c = cnt[e];
      int nt = (c + 127) >> 7;
      for (int t = 0; t < nt; t++) tilemap[k++] = (e << 16) | t;
      s += c;
    }
    segoff[NEXP] = s;
    *ntiles = k;
  }
}

__global__ void k_scatter(const int* __restrict__ dom, const int* __restrict__ pos,
                          const int* __restrict__ segoff, int* __restrict__ perm) {
  int t = blockIdx.x * 256 + threadIdx.x;
  if (t < NTOK) perm[segoff[dom[t]] + pos[t]] = t;
}

// ---------------- fp32 -> bf16 convert (row-major preserved; for x) ----------------
__global__ void k_convert(const float* __restrict__ src, unsigned short* __restrict__ dst, int n8) {
  int i = blockIdx.x * 256 + threadIdx.x;
  if (i >= n8) return;
  const float4* s = (const float4*)(src + (size_t)i * 8);
  float4 a = s[0], b = s[1];
  union { unsigned short h[8]; uint4 v; } u;
  u.h[0] = f2bf(a.x); u.h[1] = f2bf(a.y); u.h[2] = f2bf(a.z); u.h[3] = f2bf(a.w);
  u.h[4] = f2bf(b.x); u.h[5] = f2bf(b.y); u.h[6] = f2bf(b.z); u.h[7] = f2bf(b.w);
  *(uint4*)(dst + (size_t)i * 8) = u.v;
}

// gather bf16 x rows into sorted (segment) order: routed GEMM A-reads become dense
__global__ void k_gather(const unsigned short* __restrict__ xb, const int* __restrict__ perm,
                         unsigned short* __restrict__ xs) {
  int i = blockIdx.x * 256 + threadIdx.x;   // 8-elem chunks; DIM/8 = 128 chunks/row
  int row = i >> 7;
  int c = (i & 127) * 8;
  int src = perm[row];
  *(uint4*)(xs + (size_t)row * DIM + c) = *(const uint4*)(xb + (size_t)src * DIM + c);
}

// ---------------- fp32 [K][N] -> bf16 [N][K] transpose-convert (weights) ----------------
__global__ void k_transpose(const float* __restrict__ src, unsigned short* __restrict__ dst,
                            int K, int N) {
  size_t moff = (size_t)blockIdx.z * K * N;
  src += moff; dst += moff;
  __shared__ float tile[64][65];
  int n0 = blockIdx.x * 64, k0 = blockIdx.y * 64;
  int t = threadIdx.x;
  int tx = t & 15, ty = t >> 4;
#pragma unroll
  for (int i = 0; i < 4; i++) {
    int kk = ty + i * 16;
    float4 v = *(const float4*)(src + (size_t)(k0 + kk) * N + n0 + tx * 4);
    tile[kk][tx * 4 + 0] = v.x; tile[kk][tx * 4 + 1] = v.y;
    tile[kk][tx * 4 + 2] = v.z; tile[kk][tx * 4 + 3] = v.w;
  }
  __syncthreads();
#pragma unroll
  for (int i = 0; i < 2; i++) {
    int chunk = t + i * 256;
    int nl = chunk >> 3;
    int k8 = (chunk & 7) * 8;
    union { unsigned short h[8]; uint4 v; } u;
#pragma unroll
    for (int j = 0; j < 8; j++) u.h[j] = f2bf(tile[k8 + j][nl]);
    *(uint4*)(dst + (size_t)(n0 + nl) * K + k0 + k8) = u.v;
  }
}

// ---------------- MFMA core: 128x128 tile, BK=32, m97 2-barrier structure ----------------
static __device__ __forceinline__ void mfma_tile(
    const unsigned short* gA0, const unsigned short* gA1,
    const unsigned short* gB0, const unsigned short* gB1,
    unsigned short (*As)[32], unsigned short (*Bs)[32],
    int w, int lane, int K, f32x4 acc[4][4])
{
  unsigned short* lA0 = &As[0][0] + w * 1024;
  unsigned short* lA1 = lA0 + 512;
  unsigned short* lB0 = &Bs[0][0] + w * 1024;
  unsigned short* lB1 = lB0 + 512;
  int m16 = lane & 15, kh = (lane >> 4) * 8;
  int wr = (w >> 1) * 64, wc = (w & 1) * 64;
  for (int kt = 0; kt < K; kt += 32) {
    gld_lds16(gA0, lA0); gld_lds16(gA1, lA1);
    gld_lds16(gB0, lB0); gld_lds16(gB1, lB1);
    gA0 += 32; gA1 += 32; gB0 += 32; gB1 += 32;
    __syncthreads();                 // drains vmcnt (global_load_lds) + orders LDS
    bf16x8 af[4], bfr[4];
#pragma unroll
    for (int i = 0; i < 4; i++) af[i] = *(const bf16x8*)&As[wr + i * 16 + m16][kh];
#pragma unroll
    for (int j = 0; j < 4; j++) bfr[j] = *(const bf16x8*)&Bs[wc + j * 16 + m16][kh];
#pragma unroll
    for (int i = 0; i < 4; i++)
#pragma unroll
      for (int j = 0; j < 4; j++)
        acc[i][j] = __builtin_amdgcn_mfma_f32_16x16x32_bf16(af[i], bfr[j], acc[i][j], 0, 0, 0);
    __syncthreads();
  }
}

// ---------------- pass 1: h1 = gelu(A@W1+b1) AND g = sigmoid(A@Wg+bg), K=DIM ----------------
// by < 32 -> W1/gelu (Nw=FFN), else Wg/sigmoid (Nw=DIM). Shared: A=xb, rows=token.
// Routed: A=xs (sorted), tile list from tilemap; outputs stored at sorted rows (seg0+l).
template <bool ROUTED>
__global__ __launch_bounds__(256)
void k_gemm01(const unsigned short* __restrict__ A,
              const unsigned short* __restrict__ W1t,  // bf16 [(e,) FFN, DIM]
              const float* __restrict__ b1,
              const unsigned short* __restrict__ Wgt,  // bf16 [(e,) DIM, DIM]
              const float* __restrict__ bg,
              unsigned short* __restrict__ h1,
              float* __restrict__ g,
              const int* __restrict__ segoff,
              const int* __restrict__ tilemap,
              const int* __restrict__ ntilesp) {
  constexpr int NX = ROUTED ? NT_RT : NT_SH;
  int bx, by;
  map_block<NX, NY01, 8>((int)blockIdx.x, bx, by);

  int e = 0, seg0 = 0, cnt = NTOK, m0;
  if (ROUTED) {
    if (bx >= *ntilesp) return;
    int tm = tilemap[bx];
    e = tm >> 16;
    seg0 = segoff[e];
    cnt = segoff[e + 1] - seg0;
    m0 = (tm & 0xffff) << 7;
  } else {
    m0 = bx << 7;
  }

  const bool isW1 = by < (FFN / 128);
  const int n0 = (isW1 ? by : by - FFN / 128) << 7;
  const unsigned short* Bte = isW1 ? W1t + (size_t)e * FFN * DIM + (size_t)n0 * DIM
                                   : Wgt + (size_t)e * DIM * DIM + (size_t)n0 * DIM;
  const float* be = (isW1 ? b1 + (size_t)e * FFN : bg + (size_t)e * DIM) + n0;

  __shared__ unsigned short As[128][32];
  __shared__ unsigned short Bs[128][32];

  int tid = threadIdx.x, w = tid >> 6, lane = tid & 63;
  int p0 = w * 128 + lane;
  int r0 = p0 >> 2, r1 = r0 + 16;
  int kc = (p0 & 3) * 8;

  auto arow = [&](int rl) -> size_t {
    int l = m0 + rl;
    if (ROUTED && l > cnt - 1) l = cnt - 1;   // clamp (masked at store)
    return (size_t)(seg0 + l);
  };
  const unsigned short* gA0 = A + arow(r0) * DIM + kc;
  const unsigned short* gA1 = A + arow(r1) * DIM + kc;
  const unsigned short* gB0 = Bte + (size_t)r0 * DIM + kc;
  const unsigned short* gB1 = Bte + (size_t)r1 * DIM + kc;

  f32x4 acc[4][4];
#pragma unroll
  for (int i = 0; i < 4; i++)
#pragma unroll
    for (int j = 0; j < 4; j++) acc[i][j] = (f32x4){0.f, 0.f, 0.f, 0.f};

  mfma_tile(gA0, gA1, gB0, gB1, As, Bs, w, lane, DIM, acc);

  // epilogue: C/D layout col = lane&15, row = (lane>>4)*4 + reg
  int m16 = lane & 15, quad = lane >> 4;
  int wr = (w >> 1) * 64, wc = (w & 1) * 64;
#pragma unroll
  for (int i = 0; i < 4; i++) {
#pragma unroll
    for (int j = 0; j < 4; j++) {
      int cn = wc + j * 16 + m16;
      int col = n0 + cn;
#pragma unroll
      for (int r = 0; r < 4; r++) {
        int rl = wr + i * 16 + quad * 4 + r;
        int l = m0 + rl;
        if (ROUTED && l >= cnt) continue;
        float z = acc[i][j][r] + be[cn];
        size_t row = (size_t)(seg0 + l);
        if (isW1) {
          z = 0.5f * z * (1.0f + erff(z * 0.70710678118654752f));  // exact gelu
          h1[row * FFN + col] = f2bf(z);
        } else {
          z = 1.0f / (1.0f + expf(-z));
          g[row * DIM + col] = z;
        }
      }
    }
  }
}

// ---------------- pass 2: h = A@W2+b2+x; out (=/+=) g*h+(1-g)*x, K=FFN ----------------
template <bool ROUTED>
__global__ __launch_bounds__(256)
void k_gemm2(const unsigned short* __restrict__ A,     // h1 bf16 [8192, FFN] (sorted rows if ROUTED)
             const unsigned short* __restrict__ W2t,   // bf16 [(e,) DIM, FFN]
             const float* __restrict__ b2,
             const float* __restrict__ g,
             const float* __restrict__ xres,
             float* __restrict__ out,
             const int* __restrict__ perm,
             const int* __restrict__ segoff,
             const int* __restrict__ tilemap,
             const int* __restrict__ ntilesp) {
  constexpr int NX = ROUTED ? NT_RT : NT_SH;
  int bx, by;
  map_block<NX, NY2, 2>((int)blockIdx.x, bx, by);

  int e = 0, seg0 = 0, cnt = NTOK, m0;
  if (ROUTED) {
    if (bx >= *ntilesp) return;
    int tm = tilemap[bx];
    e = tm >> 16;
    seg0 = segoff[e];
    cnt = segoff[e + 1] - seg0;
    m0 = (tm & 0xffff) << 7;
  } else {
    m0 = bx << 7;
  }
  const int n0 = by << 7;
  const unsigned short* Bte = W2t + (size_t)e * DIM * FFN + (size_t)n0 * FFN;
  const float* be = b2 + (size_t)e * DIM + n0;

  __shared__ unsigned short As[128][32];
  __shared__ unsigned short Bs[128][32];

  int tid = threadIdx.x, w = tid >> 6, lane = tid & 63;
  int p0 = w * 128 + lane;
  int r0 = p0 >> 2, r1 = r0 + 16;
  int kc = (p0 & 3) * 8;

  auto arow = [&](int rl) -> size_t {
    int l = m0 + rl;
    if (ROUTED && l > cnt - 1) l = cnt - 1;
    return (size_t)(seg0 + l);
  };
  const unsigned short* gA0 = A + arow(r0) * FFN + kc;
  const unsigned short* gA1 = A + arow(r1) * FFN + kc;
  const unsigned short* gB0 = Bte + (size_t)r0 * FFN + kc;
  const unsigned short* gB1 = Bte + (size_t)r1 * FFN + kc;

  f32x4 acc[4][4];
#pragma unroll
  for (int i = 0; i < 4; i++)
#pragma unroll
    for (int j = 0; j < 4; j++) acc[i][j] = (f32x4){0.f, 0.f, 0.f, 0.f};

  mfma_tile(gA0, gA1, gB0, gB1, As, Bs, w, lane, FFN, acc);

  int m16 = lane & 15, quad = lane >> 4;
  int wr = (w >> 1) * 64, wc = (w & 1) * 64;
#pragma unroll
  for (int i = 0; i < 4; i++) {
#pragma unroll
    for (int j = 0; j < 4; j++) {
      int cn = wc + j * 16 + m16;
      int col = n0 + cn;
#pragma unroll
      for (int r = 0; r < 4; r++) {
        int rl = wr + i * 16 + quad * 4 + r;
        int l = m0 + rl;
        if (ROUTED && l >= cnt) continue;
        int lidx = seg0 + l;
        int grow = ROUTED ? perm[lidx] : l;      // global token row
        float xv = xres[(size_t)grow * DIM + col];
        float gv = g[(size_t)lidx * DIM + col];
        float h = acc[i][j][r] + be[cn] + xv;
        float o = gv * h + (1.0f - gv) * xv;
        float* po = &out[(size_t)grow * DIM + col];
        if (ROUTED) *po += o;   // unique rows per token: no atomics needed
        else        *po = o;
      }
    }
  }
}

extern "C" void kernel_launch(void* const* d_in, const int* in_sizes, int n_in,
                              void* d_out, int out_size, void* d_ws, size_t ws_size,
                              hipStream_t stream) {
  (void)in_sizes; (void)n_in; (void)out_size; (void)ws_size;
  const float* x   = (const float*)d_in[0];
  const int*   dom = (const int*)d_in[1];
  const float* sW1 = (const float*)d_in[2];
  const float* sb1 = (const float*)d_in[3];
  const float* sW2 = (const float*)d_in[4];
  const float* sb2 = (const float*)d_in[5];
  const float* sWg = (const float*)d_in[6];
  const float* sbg = (const float*)d_in[7];
  const float* dW1 = (const float*)d_in[8];
  const float* db1 = (const float*)d_in[9];
  const float* dW2 = (const float*)d_in[10];
  const float* db2 = (const float*)d_in[11];
  const float* dWg = (const float*)d_in[12];
  const float* dbg = (const float*)d_in[13];
  float* out = (float*)d_out;

  char* p = (char*)d_ws;
  auto take = [&](size_t b) { char* r = p; p += (b + 255) & ~(size_t)255; return r; };
  int* cnt     = (int*)take(NEXP * 4);
  int* segoff  = (int*)take((NEXP + 1) * 4);
  int* tilemap = (int*)take(128 * 4);
  int* ntiles  = (int*)take(4);
  int* pos     = (int*)take((size_t)NTOK * 4);
  int* perm    = (int*)take((size_t)NTOK * 4);
  unsigned short* xb   = (unsigned short*)take((size_t)NTOK * DIM * 2);
  unsigned short* xs   = (unsigned short*)take((size_t)NTOK * DIM * 2);   // sorted x
  unsigned short* h1   = (unsigned short*)take((size_t)NTOK * FFN * 2);   // reused shared->routed
  float*          g    = (float*)take((size_t)NTOK * DIM * 4);            // reused shared->routed
  unsigned short* sW1t = (unsigned short*)take((size_t)DIM * FFN * 2);
  unsigned short* sW2t = (unsigned short*)take((size_t)FFN * DIM * 2);
  unsigned short* sWgt = (unsigned short*)take((size_t)DIM * DIM * 2);
  unsigned short* dW1t = (unsigned short*)take((size_t)NEXP * DIM * FFN * 2);
  unsigned short* dW2t = (unsigned short*)take((size_t)NEXP * FFN * DIM * 2);
  unsigned short* dWgt = (unsigned short*)take((size_t)NEXP * DIM * DIM * 2);

  // routing (+ exact routed tile list)
  k_zero<<<1, 64, 0, stream>>>(cnt);
  k_count<<<NTOK / 256, 256, 0, stream>>>(dom, cnt, pos);
  k_offsets<<<1, 1, 0, stream>>>(cnt, segoff, tilemap, ntiles);
  k_scatter<<<NTOK / 256, 256, 0, stream>>>(dom, pos, segoff, perm);

  // convert x; gather sorted x; transpose-convert all weights to bf16 [N][K]
  k_convert<<<(NTOK * DIM / 8) / 256, 256, 0, stream>>>(x, xb, NTOK * DIM / 8);
  k_gather<<<(NTOK * DIM / 8) / 256, 256, 0, stream>>>(xb, perm, xs);
  k_transpose<<<dim3(FFN / 64, DIM / 64, 1),    256, 0, stream>>>(sW1, sW1t, DIM, FFN);
  k_transpose<<<dim3(DIM / 64, FFN / 64, 1),    256, 0, stream>>>(sW2, sW2t, FFN, DIM);
  k_transpose<<<dim3(DIM / 64, DIM / 64, 1),    256, 0, stream>>>(sWg, sWgt, DIM, DIM);
  k_transpose<<<dim3(FFN / 64, DIM / 64, NEXP), 256, 0, stream>>>(dW1, dW1t, DIM, FFN);
  k_transpose<<<dim3(DIM / 64, FFN / 64, NEXP), 256, 0, stream>>>(dW2, dW2t, FFN, DIM);
  k_transpose<<<dim3(DIM / 64, DIM / 64, NEXP), 256, 0, stream>>>(dWg, dWgt, DIM, DIM);

  // shared expert pass (h1+g in one dispatch, then combine; writes every out element)
  k_gemm01<false><<<NT_SH * NY01, 256, 0, stream>>>(
      xb, sW1t, sb1, sWgt, sbg, h1, g, nullptr, nullptr, nullptr);
  k_gemm2<false><<<NT_SH * NY2, 256, 0, stream>>>(
      h1, sW2t, sb2, g, x, out, nullptr, nullptr, nullptr, nullptr);

  // routed expert pass (exact tile list; accumulates into out); reuses h1/g at sorted rows
  k_gemm01<true><<<NT_RT * NY01, 256, 0, stream>>>(
      xs, dW1t, db1, dWgt, dbg, h1, g, segoff, tilemap, ntiles);
  k_gemm2<true><<<NT_RT * NY2, 256, 0, stream>>>(
      h1, dW2t, db2, g, x, out, perm, segoff, tilemap, ntiles);
}